// Round 17
// baseline (262.746 us; speedup 1.0000x reference)
//
#include <hip/hip_runtime.h>

#define NN 100000
#define NE 1600000
#define FD 128
#define NG 64
#define OUTD 64
#define NBIN 391    // ceil(NN/256)
#define NGFILL 391  // fill blocks in k_mix (4096 edges each)
#define NGEMM1 1563 // ceil(NN/64)

typedef __attribute__((ext_vector_type(8))) short bf16x8;
typedef __attribute__((ext_vector_type(4))) float f32x4;
typedef __attribute__((ext_vector_type(2))) float f32x2;
typedef __attribute__((ext_vector_type(8))) unsigned short u16x8;

static __device__ __forceinline__ void atomAddF(float* p, float v) {
    __hip_atomic_fetch_add(p, v, __ATOMIC_RELAXED, __HIP_MEMORY_SCOPE_AGENT);
}
static __device__ __forceinline__ int atomAddI(int* p, int v) {
    return __hip_atomic_fetch_add(p, v, __ATOMIC_RELAXED, __HIP_MEMORY_SCOPE_AGENT);
}
static __device__ __forceinline__ unsigned short f2bf(float f) {
    unsigned int u = __float_as_uint(f);
    u += 0x7FFFu + ((u >> 16) & 1u);
    return (unsigned short)(u >> 16);
}
static __device__ __forceinline__ unsigned char f2fp8(float v) {
    return (unsigned char)(__builtin_amdgcn_cvt_pk_fp8_f32(v, v, 0, false) & 0xff);
}

// ===== K1 k_pre: [0..390] per-BIN edge hist; [391..781] graph counts;
//                 [782..910] Wt convert + fp8 dummy rows =====
__global__ __launch_bounds__(256) void k_pre(
    const int* __restrict__ dst, const int* __restrict__ gid,
    int* __restrict__ bincnt, float* __restrict__ gcount,
    const float* __restrict__ W1, const float* __restrict__ W2,
    unsigned short* __restrict__ W1t, unsigned short* __restrict__ W2t,
    unsigned int* __restrict__ Y8dummy, unsigned int* __restrict__ Y82dummy)
{
    const int t = threadIdx.x;
    if (blockIdx.x < NBIN) {
        __shared__ int h[NBIN];
        for (int i = t; i < NBIN; i += 256) h[i] = 0;
        __syncthreads();
        int e0 = blockIdx.x * 4096;
        int e1 = min(e0 + 4096, NE);
        for (int e = e0 + t; e < e1; e += 256)
            atomicAdd(&h[dst[e] >> 8], 1);
        __syncthreads();
        for (int i = t; i < NBIN; i += 256)
            if (h[i]) atomAddI(&bincnt[i], h[i]);
    } else if (blockIdx.x < 2 * NBIN) {
        __shared__ float c[NG];
        if (t < NG) c[t] = 0.0f;
        __syncthreads();
        int i = (blockIdx.x - NBIN) * 256 + t;
        if (i < NN) atomicAdd(&c[gid[i]], 1.0f);
        __syncthreads();
        if (t < NG) {
            float v = c[t];
            if (v != 0.0f) atomAddF(&gcount[t], v);
        }
    } else {
        int idx = (blockIdx.x - 2 * NBIN) * 256 + t;
        if (idx < 32768) {
            const float* W = (idx < 16384) ? W1 : W2;
            unsigned short* Wt = (idx < 16384) ? W1t : W2t;
            int i = idx & 16383;
            int k = i >> 7, n = i & 127;
            Wt[n * 128 + k] = f2bf(W[i]);
        } else if (idx < 32768 + 32) {
            Y8dummy[idx - 32768] = 0;
        } else if (idx < 32768 + 64) {
            Y82dummy[idx - 32768 - 32] = 0;
        }
    }
}

// ===== K2: scan 391 bin counts -> pstart ; bcur init =====
__global__ void k_boff(const int* __restrict__ bincnt, int* __restrict__ pstart,
                       int* __restrict__ bcur) {
    __shared__ int s[512];
    int t = threadIdx.x;
    int v = (t < NBIN) ? bincnt[t] : 0;
    s[t] = v;
    __syncthreads();
    for (int d = 1; d < 512; d <<= 1) {
        int x = (t >= d) ? s[t - d] : 0;
        __syncthreads();
        s[t] += x;
        __syncthreads();
    }
    if (t < NBIN) {
        int p = s[t] - v;
        pstart[t] = p;
        bcur[t * 16] = p;
    }
}

// ===== no-LDS MFMA gemm1 body: Y8 (fp8) = feat @ W1 =====
static __device__ __forceinline__ void gemm_body(
    int base, const float* __restrict__ feat, const unsigned short* __restrict__ Wt,
    unsigned char* __restrict__ Y8)
{
    const int lane = threadIdx.x & 63;
    const int w = threadIdx.x >> 6;
    const int r = lane & 15;
    const int kb = lane >> 4;
    const int row = base + w * 16 + r;
    const bool rok = row < NN;

    bf16x8 a[4];
    #pragma unroll
    for (int kt = 0; kt < 4; ++kt) {
        float4 lo = {0,0,0,0}, hi = {0,0,0,0};
        if (rok) {
            const float4* p = reinterpret_cast<const float4*>(
                feat + (size_t)row * FD + kt * 32 + kb * 8);
            lo = p[0]; hi = p[1];
        }
        bf16x8 t;
        t[0] = (short)f2bf(lo.x); t[1] = (short)f2bf(lo.y);
        t[2] = (short)f2bf(lo.z); t[3] = (short)f2bf(lo.w);
        t[4] = (short)f2bf(hi.x); t[5] = (short)f2bf(hi.y);
        t[6] = (short)f2bf(hi.z); t[7] = (short)f2bf(hi.w);
        a[kt] = t;
    }

    f32x4 acc[8];
    #pragma unroll
    for (int ct = 0; ct < 8; ++ct) acc[ct] = (f32x4){0.f, 0.f, 0.f, 0.f};

    const int n = lane & 15;
    #pragma unroll
    for (int ct = 0; ct < 8; ++ct) {
        int col = ct * 16 + n;
        #pragma unroll
        for (int kt = 0; kt < 4; ++kt) {
            bf16x8 b = *reinterpret_cast<const bf16x8*>(
                Wt + (size_t)col * FD + kt * 32 + kb * 8);
            acc[ct] = __builtin_amdgcn_mfma_f32_16x16x32_bf16(a[kt], b, acc[ct], 0, 0, 0);
        }
    }

    const int rbase = base + w * 16 + (lane >> 4) * 4;
    #pragma unroll
    for (int reg = 0; reg < 4; ++reg) {
        int node = rbase + reg;
        if (node < NN) {
            #pragma unroll
            for (int ct = 0; ct < 8; ++ct)
                Y8[(size_t)node * FD + ct * 16 + n] = f2fp8(acc[ct][reg]);
        }
    }
}

// ===== K3 k_mix: [g<NGFILL] LDS-multisplit bin append; else gemm1 =====
__global__ __launch_bounds__(256) void k_mix(
    const int* __restrict__ src, const int* __restrict__ dst,
    int* __restrict__ bcur, unsigned int* __restrict__ pbuf,
    const float* __restrict__ feat, const unsigned short* __restrict__ Wt,
    unsigned char* __restrict__ Y8)
{
    int g = blockIdx.x;
    if (g >= NGFILL) {
        gemm_body((g - NGFILL) * 64, feat, Wt, Y8);
    } else {
        __shared__ int h[NBIN];
        __shared__ int lcur[NBIN];
        const int t = threadIdx.x;
        const int e0 = g * 4096;
        const int e1 = min(e0 + 4096, NE);

        for (int i = t; i < NBIN; i += 256) h[i] = 0;
        __syncthreads();
        for (int e = e0 + t; e < e1; e += 256)
            atomicAdd(&h[dst[e] >> 8], 1);
        __syncthreads();
        for (int i = t; i < NBIN; i += 256) {
            int c = h[i];
            lcur[i] = c ? atomAddI(&bcur[i * 16], c) : 0;
        }
        __syncthreads();
        for (int e = e0 + t; e < e1; e += 256) {
            int d = dst[e];
            int p = atomicAdd(&lcur[d >> 8], 1);
            pbuf[p] = ((unsigned int)(d & 255) << 17) | (unsigned int)src[e];
        }
    }
}

// ===== K4 k_fill2: bin-local CSR build (pad 4) =====
// Max pad per bin = 3*256 = 768 < 1024 region stride -> always fits.
__global__ __launch_bounds__(256) void k_fill2(
    const unsigned int* __restrict__ pbuf, const int* __restrict__ pstart,
    const int* __restrict__ bcur, int* __restrict__ degi, int* __restrict__ off,
    int* __restrict__ eidx)
{
    __shared__ int ldeg[256], lpre[256], lcur[256];
    const int b = blockIdx.x;
    const int t = threadIdx.x;
    const int st = pstart[b];
    const int en = bcur[b * 16];
    const int cnt = en - st;

    ldeg[t] = 0;
    __syncthreads();
    for (int i = t; i < cnt; i += 256)
        atomicAdd(&ldeg[(int)(pbuf[st + i] >> 17)], 1);
    __syncthreads();

    const int d = ldeg[t];
    const int rd = (d + 3) & ~3;
    lpre[t] = rd;
    __syncthreads();
    for (int dd = 1; dd < 256; dd <<= 1) {
        int x = (t >= dd) ? lpre[t - dd] : 0;
        __syncthreads();
        lpre[t] += x;
        __syncthreads();
    }

    const int ebase = st + b * 1024;            // eidx region for bin b
    const int o = ebase + lpre[t] - rd;
    const int v = (b << 8) + t;
    if (v < NN) {
        degi[v] = d;
        off[v] = o;
        for (int j = d; j < rd; ++j) eidx[o + j] = NN;   // dummy padding
    }
    lcur[t] = o;
    __syncthreads();

    for (int i = t; i < cnt; i += 256) {
        unsigned int pk = pbuf[st + i];
        int dl = (int)(pk >> 17);
        int s  = (int)(pk & 0x1FFFF);
        int p = atomicAdd(&lcur[dl], 1);
        eidx[p] = s;
    }
}

// ===== K5 k_aggmm: agg layer-1 (all fp8, chunk-4) + fused M=16 gemm2 -> Y82 =====
__global__ __launch_bounds__(256) void k_aggmm(
    const unsigned char* __restrict__ Y8, const int* __restrict__ off,
    const int* __restrict__ degi, const int* __restrict__ eidx,
    const float* __restrict__ bias, const unsigned short* __restrict__ Wt2,
    unsigned char* __restrict__ Y82)
{
    __shared__ unsigned short At[16 * FD];   // 4 KB, swizzled rows of 256B
    const int t = blockIdx.x * 256 + threadIdx.x;
    const int v = t >> 4;
    const int l = threadIdx.x & 15;
    const int gb = threadIdx.x & 48;
    const int e0 = off[v];
    const int d  = degi[v];
    const int pd = (d + 3) & ~3;

    float a[8];
    #pragma unroll
    for (int j = 0; j < 8; ++j) a[j] = 0.0f;

    const uint2* Y8v = reinterpret_cast<const uint2*>(Y8);
    const int eend = e0 + pd;
    for (int e = e0; e < eend; e += 4) {
        int myidx = eidx[e + (l & 3)];
        #pragma unroll
        for (int j = 0; j < 4; ++j) {
            int s = __shfl(myidx, gb + j, 64);
            uint2 q = Y8v[(size_t)s * 16 + l];
            f32x2 v0 = __builtin_amdgcn_cvt_pk_f32_fp8((int)q.x, false);
            f32x2 v1 = __builtin_amdgcn_cvt_pk_f32_fp8((int)q.x, true);
            f32x2 v2 = __builtin_amdgcn_cvt_pk_f32_fp8((int)q.y, false);
            f32x2 v3 = __builtin_amdgcn_cvt_pk_f32_fp8((int)q.y, true);
            a[0] += v0[0]; a[1] += v0[1]; a[2] += v1[0]; a[3] += v1[1];
            a[4] += v2[0]; a[5] += v2[1]; a[6] += v3[0]; a[7] += v3[1];
        }
    }

    const float inv = 1.0f / fmaxf((float)d, 1.0f);
    uint2 qs = Y8v[(size_t)v * 16 + l];          // fp8 self term
    f32x2 s0 = __builtin_amdgcn_cvt_pk_f32_fp8((int)qs.x, false);
    f32x2 s1 = __builtin_amdgcn_cvt_pk_f32_fp8((int)qs.x, true);
    f32x2 s2 = __builtin_amdgcn_cvt_pk_f32_fp8((int)qs.y, false);
    f32x2 s3 = __builtin_amdgcn_cvt_pk_f32_fp8((int)qs.y, true);
    float sf[8] = { s0[0], s0[1], s1[0], s1[1], s2[0], s2[1], s3[0], s3[1] };
    const float4* bp = reinterpret_cast<const float4*>(bias + l * 8);
    float4 b0 = bp[0], b1 = bp[1];
    const float* bb[8] = { &b0.x, &b0.y, &b0.z, &b0.w, &b1.x, &b1.y, &b1.z, &b1.w };

    // h1 (bf16) -> LDS A-tile, swizzled
    {
        u16x8 o;
        #pragma unroll
        for (int j = 0; j < 8; ++j)
            o[j] = f2bf(fmaxf(sf[j] + a[j] * inv + *bb[j], 0.0f));
        int g = threadIdx.x >> 4;
        char* AtB = reinterpret_cast<char*>(At);
        *reinterpret_cast<u16x8*>(AtB + g * 256 + ((l * 16) ^ ((g & 7) << 4))) = o;
    }
    __syncthreads();

    // M=16 GEMM: Y2[16x128] = At @ W2 ; wave w covers cols [32w, 32w+32)
    {
        const int lane = threadIdx.x & 63;
        const int w = threadIdx.x >> 6;
        const int r = lane & 15;
        const int kb = lane >> 4;
        const int n = lane & 15;
        char* AtB = reinterpret_cast<char*>(At);

        bf16x8 af[4];
        #pragma unroll
        for (int kt = 0; kt < 4; ++kt)
            af[kt] = *reinterpret_cast<bf16x8*>(
                AtB + r * 256 + ((kt * 64 + kb * 16) ^ ((r & 7) << 4)));

        f32x4 acc[2];
        acc[0] = (f32x4){0.f, 0.f, 0.f, 0.f};
        acc[1] = (f32x4){0.f, 0.f, 0.f, 0.f};
        #pragma unroll
        for (int ct = 0; ct < 2; ++ct) {
            int col = w * 32 + ct * 16 + n;
            #pragma unroll
            for (int kt = 0; kt < 4; ++kt) {
                bf16x8 bf = *reinterpret_cast<const bf16x8*>(
                    Wt2 + (size_t)col * FD + kt * 32 + kb * 8);
                acc[ct] = __builtin_amdgcn_mfma_f32_16x16x32_bf16(af[kt], bf, acc[ct], 0, 0, 0);
            }
        }

        const int nb = blockIdx.x * 16 + (lane >> 4) * 4;
        #pragma unroll
        for (int reg = 0; reg < 4; ++reg) {
            #pragma unroll
            for (int ct = 0; ct < 2; ++ct)
                Y82[(size_t)(nb + reg) * FD + w * 32 + ct * 16 + n] = f2fp8(acc[ct][reg]);
        }
    }
}

// ===== K6 k_aggp: agg layer-2 (all-fp8, chunk-4) + per-graph pooling =====
__global__ __launch_bounds__(256) void k_aggp(
    const unsigned char* __restrict__ Y82, const int* __restrict__ off,
    const int* __restrict__ degi, const int* __restrict__ eidx,
    const float* __restrict__ bias,
    const int* __restrict__ gid, float* __restrict__ hg_sum)
{
    __shared__ float hl[FD];
    if (threadIdx.x < FD) hl[threadIdx.x] = 0.0f;
    int gid0 = gid[blockIdx.x * 16];
    __syncthreads();

    const int t = blockIdx.x * 256 + threadIdx.x;
    const int v = t >> 4;
    const int l = threadIdx.x & 15;
    const int gb = threadIdx.x & 48;
    const int e0 = off[v];
    const int d  = degi[v];
    const int pd = (d + 3) & ~3;

    float a[8];
    #pragma unroll
    for (int j = 0; j < 8; ++j) a[j] = 0.0f;

    const uint2* Y8v = reinterpret_cast<const uint2*>(Y82);
    const int eend = e0 + pd;
    for (int e = e0; e < eend; e += 4) {
        int myidx = eidx[e + (l & 3)];
        #pragma unroll
        for (int j = 0; j < 4; ++j) {
            int s = __shfl(myidx, gb + j, 64);
            uint2 q = Y8v[(size_t)s * 16 + l];
            f32x2 v0 = __builtin_amdgcn_cvt_pk_f32_fp8((int)q.x, false);
            f32x2 v1 = __builtin_amdgcn_cvt_pk_f32_fp8((int)q.x, true);
            f32x2 v2 = __builtin_amdgcn_cvt_pk_f32_fp8((int)q.y, false);
            f32x2 v3 = __builtin_amdgcn_cvt_pk_f32_fp8((int)q.y, true);
            a[0] += v0[0]; a[1] += v0[1]; a[2] += v1[0]; a[3] += v1[1];
            a[4] += v2[0]; a[5] += v2[1]; a[6] += v3[0]; a[7] += v3[1];
        }
    }

    const float inv = 1.0f / fmaxf((float)d, 1.0f);
    uint2 qs = Y8v[(size_t)v * 16 + l];
    f32x2 s0 = __builtin_amdgcn_cvt_pk_f32_fp8((int)qs.x, false);
    f32x2 s1 = __builtin_amdgcn_cvt_pk_f32_fp8((int)qs.x, true);
    f32x2 s2 = __builtin_amdgcn_cvt_pk_f32_fp8((int)qs.y, false);
    f32x2 s3 = __builtin_amdgcn_cvt_pk_f32_fp8((int)qs.y, true);
    float sf[8] = { s0[0], s0[1], s1[0], s1[1], s2[0], s2[1], s3[0], s3[1] };
    const float4* bp = reinterpret_cast<const float4*>(bias + l * 8);
    float4 b0 = bp[0], b1 = bp[1];
    const float* bb[8] = { &b0.x, &b0.y, &b0.z, &b0.w, &b1.x, &b1.y, &b1.z, &b1.w };

    float hv[8];
    #pragma unroll
    for (int j = 0; j < 8; ++j)
        hv[j] = fmaxf(sf[j] + a[j] * inv + *bb[j], 0.0f);

    int g = gid[v];
    int fo = l * 8;
    if (g == gid0) {
        #pragma unroll
        for (int j = 0; j < 8; ++j) atomicAdd(&hl[fo + j], hv[j]);
    } else {
        #pragma unroll
        for (int j = 0; j < 8; ++j) atomAddF(&hg_sum[(size_t)g * FD + fo + j], hv[j]);
    }
    __syncthreads();
    if (threadIdx.x < FD)
        atomAddF(&hg_sum[(size_t)gid0 * FD + threadIdx.x], hl[threadIdx.x]);
}

// ===== K7 fused decoder: one block per graph =====
__global__ __launch_bounds__(128) void k_dec(
    const float* __restrict__ hg_sum, const float* __restrict__ gcount,
    const float* __restrict__ Wd1, const float* __restrict__ bd1,
    const float* __restrict__ Wd2, const float* __restrict__ bd2,
    float* __restrict__ out)
{
    __shared__ float hgL[FD];
    __shared__ float t1L[FD];
    const int g = blockIdx.x;
    const int t = threadIdx.x;
    const float invc = 1.0f / fmaxf(gcount[g], 1.0f);

    float v = hg_sum[(size_t)g * FD + t] * invc;
    hgL[t] = v;
    out[(size_t)g * FD + t] = v;
    __syncthreads();

    float acc = bd1[t];
    #pragma unroll 8
    for (int k = 0; k < FD; ++k)
        acc += hgL[k] * Wd1[k * FD + t];
    t1L[t] = fmaxf(acc, 0.0f);
    __syncthreads();

    if (t < OUTD) {
        float acc2 = bd2[t];
        #pragma unroll 8
        for (int k = 0; k < FD; ++k)
            acc2 += t1L[k] * Wd2[k * OUTD + t];
        out[NG * FD + (size_t)g * OUTD + t] = acc2;
    }
}

extern "C" void kernel_launch(void* const* d_in, const int* in_sizes, int n_in,
                              void* d_out, int out_size, void* d_ws, size_t ws_size,
                              hipStream_t stream) {
    const float* feat = (const float*)d_in[0];
    const int*   src  = (const int*)d_in[1];
    const int*   dst  = (const int*)d_in[2];
    const int*   gid  = (const int*)d_in[3];
    const float* W1   = (const float*)d_in[4];
    const float* b1   = (const float*)d_in[5];
    const float* W2   = (const float*)d_in[6];
    const float* b2   = (const float*)d_in[7];
    const float* Wd1  = (const float*)d_in[8];
    const float* bd1  = (const float*)d_in[9];
    const float* Wd2  = (const float*)d_in[10];
    const float* bd2  = (const float*)d_in[11];
    float* out = (float*)d_out;

    // workspace layout (4-byte-word offsets)
    char* wsb = (char*)d_ws;
    int*   bincnt = (int*)wsb;                                 // [512]
    float* gcount = (float*)(wsb + 512ll * 4);                 // [64]
    float* hg_sum = (float*)(wsb + 576ll * 4);                 // [8192]
    int*   pstart = (int*)(wsb + 8768ll * 4);                  // [512]
    int*   bcur   = (int*)(wsb + 9280ll * 4);                  // [6256] line-padded
    int*   degi   = (int*)(wsb + 15536ll * 4);                 // [100000]
    int*   off    = (int*)(wsb + 115536ll * 4);                // [100000]
    int*   eidx   = (int*)(wsb + 215536ll * 4);                // [2400800] padded CSR (pad 4)
    unsigned int* pbuf = (unsigned int*)(wsb + 2616336ll * 4); // [1600000]
    unsigned short* W1t = (unsigned short*)(wsb + 4216336ll * 4);  // bf16 [16384]
    unsigned short* W2t = (unsigned short*)(wsb + 4224528ll * 4);  // bf16 [16384]
    unsigned char*  Y8  = (unsigned char*)(wsb + 4232720ll * 4);   // fp8 [(NN+1)*128]
    unsigned char*  Y82 = (unsigned char*)(wsb + 7432752ll * 4);   // fp8 [(NN+1)*128]

    // zero bincnt + gcount + hg_sum
    hipMemsetAsync(d_ws, 0, (size_t)8768 * 4, stream);

    // K1: bin hist || graph counts || Wt + dummy rows
    k_pre<<<2 * NBIN + 129, 256, 0, stream>>>(dst, gid, bincnt, gcount, W1, W2,
                                              W1t, W2t,
                                              (unsigned int*)(Y8 + (size_t)NN * FD),
                                              (unsigned int*)(Y82 + (size_t)NN * FD));
    // K2: bin scan
    k_boff<<<1, 512, 0, stream>>>(bincnt, pstart, bcur);
    // K3: LDS-multisplit bin append (first NGFILL blocks) || gemm1
    k_mix<<<NGFILL + NGEMM1, 256, 0, stream>>>(src, dst, bcur, pbuf, feat, W1t, Y8);
    // K4: bin-local CSR build (pad 4)
    k_fill2<<<NBIN, 256, 0, stream>>>(pbuf, pstart, bcur, degi, off, eidx);
    // K5: agg1 + fused gemm2 -> Y82
    k_aggmm<<<NN / 16, 256, 0, stream>>>(Y8, off, degi, eidx, b1, W2t, Y82);
    // K6: agg2 + per-graph pooling
    k_aggp<<<NN / 16, 256, 0, stream>>>(Y82, off, degi, eidx, b2, gid, hg_sum);
    // K7: pool divide + decoder
    k_dec<<<NG, 128, 0, stream>>>(hg_sum, gcount, Wd1, bd1, Wd2, bd2, out);
}

// Round 18
// 254.107 us; speedup vs baseline: 1.0340x; 1.0340x over previous
//
#include <hip/hip_runtime.h>

#define NN 100000
#define NE 1600000
#define FD 128
#define NG 64
#define OUTD 64
#define NBIN 391    // ceil(NN/256)
#define NGFILL 391  // fill blocks in k_mix (4096 edges each)
#define NGEMM1 1563 // ceil(NN/64)

typedef __attribute__((ext_vector_type(8))) short bf16x8;
typedef __attribute__((ext_vector_type(4))) float f32x4;
typedef __attribute__((ext_vector_type(2))) float f32x2;
typedef __attribute__((ext_vector_type(8))) unsigned short u16x8;

static __device__ __forceinline__ void atomAddF(float* p, float v) {
    __hip_atomic_fetch_add(p, v, __ATOMIC_RELAXED, __HIP_MEMORY_SCOPE_AGENT);
}
static __device__ __forceinline__ int atomAddI(int* p, int v) {
    return __hip_atomic_fetch_add(p, v, __ATOMIC_RELAXED, __HIP_MEMORY_SCOPE_AGENT);
}
static __device__ __forceinline__ unsigned short f2bf(float f) {
    unsigned int u = __float_as_uint(f);
    u += 0x7FFFu + ((u >> 16) & 1u);
    return (unsigned short)(u >> 16);
}
static __device__ __forceinline__ unsigned char f2fp8(float v) {
    return (unsigned char)(__builtin_amdgcn_cvt_pk_fp8_f32(v, v, 0, false) & 0xff);
}

// ===== K1 k_pre: [0..390] per-BIN edge hist; [391..781] graph counts;
//                 [782..910] Wt convert + fp8 dummy rows =====
__global__ __launch_bounds__(256) void k_pre(
    const int* __restrict__ dst, const int* __restrict__ gid,
    int* __restrict__ bincnt, float* __restrict__ gcount,
    const float* __restrict__ W1, const float* __restrict__ W2,
    unsigned short* __restrict__ W1t, unsigned short* __restrict__ W2t,
    unsigned int* __restrict__ Y8dummy, unsigned int* __restrict__ Y82dummy)
{
    const int t = threadIdx.x;
    if (blockIdx.x < NBIN) {
        __shared__ int h[NBIN];
        for (int i = t; i < NBIN; i += 256) h[i] = 0;
        __syncthreads();
        int e0 = blockIdx.x * 4096;
        int e1 = min(e0 + 4096, NE);
        for (int e = e0 + t; e < e1; e += 256)
            atomicAdd(&h[dst[e] >> 8], 1);
        __syncthreads();
        for (int i = t; i < NBIN; i += 256)
            if (h[i]) atomAddI(&bincnt[i], h[i]);
    } else if (blockIdx.x < 2 * NBIN) {
        __shared__ float c[NG];
        if (t < NG) c[t] = 0.0f;
        __syncthreads();
        int i = (blockIdx.x - NBIN) * 256 + t;
        if (i < NN) atomicAdd(&c[gid[i]], 1.0f);
        __syncthreads();
        if (t < NG) {
            float v = c[t];
            if (v != 0.0f) atomAddF(&gcount[t], v);
        }
    } else {
        int idx = (blockIdx.x - 2 * NBIN) * 256 + t;
        if (idx < 32768) {
            const float* W = (idx < 16384) ? W1 : W2;
            unsigned short* Wt = (idx < 16384) ? W1t : W2t;
            int i = idx & 16383;
            int k = i >> 7, n = i & 127;
            Wt[n * 128 + k] = f2bf(W[i]);
        } else if (idx < 32768 + 32) {
            Y8dummy[idx - 32768] = 0;
        } else if (idx < 32768 + 64) {
            Y82dummy[idx - 32768 - 32] = 0;
        }
    }
}

// ===== K2: scan 391 bin counts -> pstart ; bcur init =====
__global__ void k_boff(const int* __restrict__ bincnt, int* __restrict__ pstart,
                       int* __restrict__ bcur) {
    __shared__ int s[512];
    int t = threadIdx.x;
    int v = (t < NBIN) ? bincnt[t] : 0;
    s[t] = v;
    __syncthreads();
    for (int d = 1; d < 512; d <<= 1) {
        int x = (t >= d) ? s[t - d] : 0;
        __syncthreads();
        s[t] += x;
        __syncthreads();
    }
    if (t < NBIN) {
        int p = s[t] - v;
        pstart[t] = p;
        bcur[t * 16] = p;
    }
}

// ===== no-LDS MFMA gemm1 body: Y8 (fp8) = feat @ W1 =====
static __device__ __forceinline__ void gemm_body(
    int base, const float* __restrict__ feat, const unsigned short* __restrict__ Wt,
    unsigned char* __restrict__ Y8)
{
    const int lane = threadIdx.x & 63;
    const int w = threadIdx.x >> 6;
    const int r = lane & 15;
    const int kb = lane >> 4;
    const int row = base + w * 16 + r;
    const bool rok = row < NN;

    bf16x8 a[4];
    #pragma unroll
    for (int kt = 0; kt < 4; ++kt) {
        float4 lo = {0,0,0,0}, hi = {0,0,0,0};
        if (rok) {
            const float4* p = reinterpret_cast<const float4*>(
                feat + (size_t)row * FD + kt * 32 + kb * 8);
            lo = p[0]; hi = p[1];
        }
        bf16x8 t;
        t[0] = (short)f2bf(lo.x); t[1] = (short)f2bf(lo.y);
        t[2] = (short)f2bf(lo.z); t[3] = (short)f2bf(lo.w);
        t[4] = (short)f2bf(hi.x); t[5] = (short)f2bf(hi.y);
        t[6] = (short)f2bf(hi.z); t[7] = (short)f2bf(hi.w);
        a[kt] = t;
    }

    f32x4 acc[8];
    #pragma unroll
    for (int ct = 0; ct < 8; ++ct) acc[ct] = (f32x4){0.f, 0.f, 0.f, 0.f};

    const int n = lane & 15;
    #pragma unroll
    for (int ct = 0; ct < 8; ++ct) {
        int col = ct * 16 + n;
        #pragma unroll
        for (int kt = 0; kt < 4; ++kt) {
            bf16x8 b = *reinterpret_cast<const bf16x8*>(
                Wt + (size_t)col * FD + kt * 32 + kb * 8);
            acc[ct] = __builtin_amdgcn_mfma_f32_16x16x32_bf16(a[kt], b, acc[ct], 0, 0, 0);
        }
    }

    const int rbase = base + w * 16 + (lane >> 4) * 4;
    #pragma unroll
    for (int reg = 0; reg < 4; ++reg) {
        int node = rbase + reg;
        if (node < NN) {
            #pragma unroll
            for (int ct = 0; ct < 8; ++ct)
                Y8[(size_t)node * FD + ct * 16 + n] = f2fp8(acc[ct][reg]);
        }
    }
}

// ===== K3 k_mix: [g<NGFILL] LDS-multisplit bin append; else gemm1 =====
__global__ __launch_bounds__(256) void k_mix(
    const int* __restrict__ src, const int* __restrict__ dst,
    int* __restrict__ bcur, unsigned int* __restrict__ pbuf,
    const float* __restrict__ feat, const unsigned short* __restrict__ Wt,
    unsigned char* __restrict__ Y8)
{
    int g = blockIdx.x;
    if (g >= NGFILL) {
        gemm_body((g - NGFILL) * 64, feat, Wt, Y8);
    } else {
        __shared__ int h[NBIN];
        __shared__ int lcur[NBIN];
        const int t = threadIdx.x;
        const int e0 = g * 4096;
        const int e1 = min(e0 + 4096, NE);

        for (int i = t; i < NBIN; i += 256) h[i] = 0;
        __syncthreads();
        for (int e = e0 + t; e < e1; e += 256)
            atomicAdd(&h[dst[e] >> 8], 1);
        __syncthreads();
        for (int i = t; i < NBIN; i += 256) {
            int c = h[i];
            lcur[i] = c ? atomAddI(&bcur[i * 16], c) : 0;
        }
        __syncthreads();
        for (int e = e0 + t; e < e1; e += 256) {
            int d = dst[e];
            int p = atomicAdd(&lcur[d >> 8], 1);
            pbuf[p] = ((unsigned int)(d & 255) << 17) | (unsigned int)src[e];
        }
    }
}

// ===== K4 k_fill2: bin-local CSR build (pad 8) =====
__global__ __launch_bounds__(256) void k_fill2(
    const unsigned int* __restrict__ pbuf, const int* __restrict__ pstart,
    const int* __restrict__ bcur, int* __restrict__ degi, int* __restrict__ off,
    int* __restrict__ eidx)
{
    __shared__ int ldeg[256], lpre[256], lcur[256];
    const int b = blockIdx.x;
    const int t = threadIdx.x;
    const int st = pstart[b];
    const int en = bcur[b * 16];
    const int cnt = en - st;

    ldeg[t] = 0;
    __syncthreads();
    for (int i = t; i < cnt; i += 256)
        atomicAdd(&ldeg[(int)(pbuf[st + i] >> 17)], 1);
    __syncthreads();

    const int d = ldeg[t];
    const int rd = (d + 7) & ~7;
    lpre[t] = rd;
    __syncthreads();
    for (int dd = 1; dd < 256; dd <<= 1) {
        int x = (t >= dd) ? lpre[t - dd] : 0;
        __syncthreads();
        lpre[t] += x;
        __syncthreads();
    }

    const int ebase = st + b * 2048;            // eidx region for bin b
    const int o = ebase + lpre[t] - rd;
    const int v = (b << 8) + t;
    if (v < NN) {
        degi[v] = d;
        off[v] = o;
        for (int j = d; j < rd; ++j) eidx[o + j] = NN;   // dummy padding
    }
    lcur[t] = o;
    __syncthreads();

    for (int i = t; i < cnt; i += 256) {
        unsigned int pk = pbuf[st + i];
        int dl = (int)(pk >> 17);
        int s  = (int)(pk & 0x1FFFF);
        int p = atomicAdd(&lcur[dl], 1);
        eidx[p] = s;
    }
}

// ===== K5 k_aggmm: agg layer-1 (all fp8, chunk-8) + fused M=16 gemm2 -> Y82 =====
__global__ __launch_bounds__(256) void k_aggmm(
    const unsigned char* __restrict__ Y8, const int* __restrict__ off,
    const int* __restrict__ degi, const int* __restrict__ eidx,
    const float* __restrict__ bias, const unsigned short* __restrict__ Wt2,
    unsigned char* __restrict__ Y82)
{
    __shared__ unsigned short At[16 * FD];   // 4 KB, swizzled rows of 256B
    const int t = blockIdx.x * 256 + threadIdx.x;
    const int v = t >> 4;
    const int l = threadIdx.x & 15;
    const int gb = threadIdx.x & 48;
    const int e0 = off[v];
    const int d  = degi[v];
    const int pd = (d + 7) & ~7;

    float a[8];
    #pragma unroll
    for (int j = 0; j < 8; ++j) a[j] = 0.0f;

    const uint2* Y8v = reinterpret_cast<const uint2*>(Y8);
    const int eend = e0 + pd;
    for (int e = e0; e < eend; e += 8) {
        int myidx = eidx[e + (l & 7)];
        #pragma unroll
        for (int j = 0; j < 8; ++j) {
            int s = __shfl(myidx, gb + j, 64);
            uint2 q = Y8v[(size_t)s * 16 + l];
            f32x2 v0 = __builtin_amdgcn_cvt_pk_f32_fp8((int)q.x, false);
            f32x2 v1 = __builtin_amdgcn_cvt_pk_f32_fp8((int)q.x, true);
            f32x2 v2 = __builtin_amdgcn_cvt_pk_f32_fp8((int)q.y, false);
            f32x2 v3 = __builtin_amdgcn_cvt_pk_f32_fp8((int)q.y, true);
            a[0] += v0[0]; a[1] += v0[1]; a[2] += v1[0]; a[3] += v1[1];
            a[4] += v2[0]; a[5] += v2[1]; a[6] += v3[0]; a[7] += v3[1];
        }
    }

    const float inv = 1.0f / fmaxf((float)d, 1.0f);
    uint2 qs = Y8v[(size_t)v * 16 + l];          // fp8 self term
    f32x2 s0 = __builtin_amdgcn_cvt_pk_f32_fp8((int)qs.x, false);
    f32x2 s1 = __builtin_amdgcn_cvt_pk_f32_fp8((int)qs.x, true);
    f32x2 s2 = __builtin_amdgcn_cvt_pk_f32_fp8((int)qs.y, false);
    f32x2 s3 = __builtin_amdgcn_cvt_pk_f32_fp8((int)qs.y, true);
    float sf[8] = { s0[0], s0[1], s1[0], s1[1], s2[0], s2[1], s3[0], s3[1] };
    const float4* bp = reinterpret_cast<const float4*>(bias + l * 8);
    float4 b0 = bp[0], b1 = bp[1];
    const float* bb[8] = { &b0.x, &b0.y, &b0.z, &b0.w, &b1.x, &b1.y, &b1.z, &b1.w };

    // h1 (bf16) -> LDS A-tile, swizzled
    {
        u16x8 o;
        #pragma unroll
        for (int j = 0; j < 8; ++j)
            o[j] = f2bf(fmaxf(sf[j] + a[j] * inv + *bb[j], 0.0f));
        int g = threadIdx.x >> 4;
        char* AtB = reinterpret_cast<char*>(At);
        *reinterpret_cast<u16x8*>(AtB + g * 256 + ((l * 16) ^ ((g & 7) << 4))) = o;
    }
    __syncthreads();

    // M=16 GEMM: Y2[16x128] = At @ W2 ; wave w covers cols [32w, 32w+32)
    {
        const int lane = threadIdx.x & 63;
        const int w = threadIdx.x >> 6;
        const int r = lane & 15;
        const int kb = lane >> 4;
        const int n = lane & 15;
        char* AtB = reinterpret_cast<char*>(At);

        bf16x8 af[4];
        #pragma unroll
        for (int kt = 0; kt < 4; ++kt)
            af[kt] = *reinterpret_cast<bf16x8*>(
                AtB + r * 256 + ((kt * 64 + kb * 16) ^ ((r & 7) << 4)));

        f32x4 acc[2];
        acc[0] = (f32x4){0.f, 0.f, 0.f, 0.f};
        acc[1] = (f32x4){0.f, 0.f, 0.f, 0.f};
        #pragma unroll
        for (int ct = 0; ct < 2; ++ct) {
            int col = w * 32 + ct * 16 + n;
            #pragma unroll
            for (int kt = 0; kt < 4; ++kt) {
                bf16x8 bf = *reinterpret_cast<const bf16x8*>(
                    Wt2 + (size_t)col * FD + kt * 32 + kb * 8);
                acc[ct] = __builtin_amdgcn_mfma_f32_16x16x32_bf16(af[kt], bf, acc[ct], 0, 0, 0);
            }
        }

        const int nb = blockIdx.x * 16 + (lane >> 4) * 4;
        #pragma unroll
        for (int reg = 0; reg < 4; ++reg) {
            #pragma unroll
            for (int ct = 0; ct < 2; ++ct)
                Y82[(size_t)(nb + reg) * FD + w * 32 + ct * 16 + n] = f2fp8(acc[ct][reg]);
        }
    }
}

// ===== K6 k_aggp: agg layer-2 (all-fp8, chunk-8) + per-graph pooling =====
__global__ __launch_bounds__(256) void k_aggp(
    const unsigned char* __restrict__ Y82, const int* __restrict__ off,
    const int* __restrict__ degi, const int* __restrict__ eidx,
    const float* __restrict__ bias,
    const int* __restrict__ gid, float* __restrict__ hg_sum)
{
    __shared__ float hl[FD];
    if (threadIdx.x < FD) hl[threadIdx.x] = 0.0f;
    int gid0 = gid[blockIdx.x * 16];
    __syncthreads();

    const int t = blockIdx.x * 256 + threadIdx.x;
    const int v = t >> 4;
    const int l = threadIdx.x & 15;
    const int gb = threadIdx.x & 48;
    const int e0 = off[v];
    const int d  = degi[v];
    const int pd = (d + 7) & ~7;

    float a[8];
    #pragma unroll
    for (int j = 0; j < 8; ++j) a[j] = 0.0f;

    const uint2* Y8v = reinterpret_cast<const uint2*>(Y82);
    const int eend = e0 + pd;
    for (int e = e0; e < eend; e += 8) {
        int myidx = eidx[e + (l & 7)];
        #pragma unroll
        for (int j = 0; j < 8; ++j) {
            int s = __shfl(myidx, gb + j, 64);
            uint2 q = Y8v[(size_t)s * 16 + l];
            f32x2 v0 = __builtin_amdgcn_cvt_pk_f32_fp8((int)q.x, false);
            f32x2 v1 = __builtin_amdgcn_cvt_pk_f32_fp8((int)q.x, true);
            f32x2 v2 = __builtin_amdgcn_cvt_pk_f32_fp8((int)q.y, false);
            f32x2 v3 = __builtin_amdgcn_cvt_pk_f32_fp8((int)q.y, true);
            a[0] += v0[0]; a[1] += v0[1]; a[2] += v1[0]; a[3] += v1[1];
            a[4] += v2[0]; a[5] += v2[1]; a[6] += v3[0]; a[7] += v3[1];
        }
    }

    const float inv = 1.0f / fmaxf((float)d, 1.0f);
    uint2 qs = Y8v[(size_t)v * 16 + l];
    f32x2 s0 = __builtin_amdgcn_cvt_pk_f32_fp8((int)qs.x, false);
    f32x2 s1 = __builtin_amdgcn_cvt_pk_f32_fp8((int)qs.x, true);
    f32x2 s2 = __builtin_amdgcn_cvt_pk_f32_fp8((int)qs.y, false);
    f32x2 s3 = __builtin_amdgcn_cvt_pk_f32_fp8((int)qs.y, true);
    float sf[8] = { s0[0], s0[1], s1[0], s1[1], s2[0], s2[1], s3[0], s3[1] };
    const float4* bp = reinterpret_cast<const float4*>(bias + l * 8);
    float4 b0 = bp[0], b1 = bp[1];
    const float* bb[8] = { &b0.x, &b0.y, &b0.z, &b0.w, &b1.x, &b1.y, &b1.z, &b1.w };

    float hv[8];
    #pragma unroll
    for (int j = 0; j < 8; ++j)
        hv[j] = fmaxf(sf[j] + a[j] * inv + *bb[j], 0.0f);

    int g = gid[v];
    int fo = l * 8;
    if (g == gid0) {
        #pragma unroll
        for (int j = 0; j < 8; ++j) atomicAdd(&hl[fo + j], hv[j]);
    } else {
        #pragma unroll
        for (int j = 0; j < 8; ++j) atomAddF(&hg_sum[(size_t)g * FD + fo + j], hv[j]);
    }
    __syncthreads();
    if (threadIdx.x < FD)
        atomAddF(&hg_sum[(size_t)gid0 * FD + threadIdx.x], hl[threadIdx.x]);
}

// ===== K7 fused decoder: one block per graph =====
__global__ __launch_bounds__(128) void k_dec(
    const float* __restrict__ hg_sum, const float* __restrict__ gcount,
    const float* __restrict__ Wd1, const float* __restrict__ bd1,
    const float* __restrict__ Wd2, const float* __restrict__ bd2,
    float* __restrict__ out)
{
    __shared__ float hgL[FD];
    __shared__ float t1L[FD];
    const int g = blockIdx.x;
    const int t = threadIdx.x;
    const float invc = 1.0f / fmaxf(gcount[g], 1.0f);

    float v = hg_sum[(size_t)g * FD + t] * invc;
    hgL[t] = v;
    out[(size_t)g * FD + t] = v;
    __syncthreads();

    float acc = bd1[t];
    #pragma unroll 8
    for (int k = 0; k < FD; ++k)
        acc += hgL[k] * Wd1[k * FD + t];
    t1L[t] = fmaxf(acc, 0.0f);
    __syncthreads();

    if (t < OUTD) {
        float acc2 = bd2[t];
        #pragma unroll 8
        for (int k = 0; k < FD; ++k)
            acc2 += t1L[k] * Wd2[k * OUTD + t];
        out[NG * FD + (size_t)g * OUTD + t] = acc2;
    }
}

extern "C" void kernel_launch(void* const* d_in, const int* in_sizes, int n_in,
                              void* d_out, int out_size, void* d_ws, size_t ws_size,
                              hipStream_t stream) {
    const float* feat = (const float*)d_in[0];
    const int*   src  = (const int*)d_in[1];
    const int*   dst  = (const int*)d_in[2];
    const int*   gid  = (const int*)d_in[3];
    const float* W1   = (const float*)d_in[4];
    const float* b1   = (const float*)d_in[5];
    const float* W2   = (const float*)d_in[6];
    const float* b2   = (const float*)d_in[7];
    const float* Wd1  = (const float*)d_in[8];
    const float* bd1  = (const float*)d_in[9];
    const float* Wd2  = (const float*)d_in[10];
    const float* bd2  = (const float*)d_in[11];
    float* out = (float*)d_out;

    // workspace layout (4-byte-word offsets)
    char* wsb = (char*)d_ws;
    int*   bincnt = (int*)wsb;                                 // [512]
    float* gcount = (float*)(wsb + 512ll * 4);                 // [64]
    float* hg_sum = (float*)(wsb + 576ll * 4);                 // [8192]
    int*   pstart = (int*)(wsb + 8768ll * 4);                  // [512]
    int*   bcur   = (int*)(wsb + 9280ll * 4);                  // [6256] line-padded
    int*   degi   = (int*)(wsb + 15536ll * 4);                 // [100000]
    int*   off    = (int*)(wsb + 115536ll * 4);                // [100000]
    int*   eidx   = (int*)(wsb + 215536ll * 4);                // [2400800] padded CSR (pad 8)
    unsigned int* pbuf = (unsigned int*)(wsb + 2616336ll * 4); // [1600000]
    unsigned short* W1t = (unsigned short*)(wsb + 4216336ll * 4);  // bf16 [16384]
    unsigned short* W2t = (unsigned short*)(wsb + 4224528ll * 4);  // bf16 [16384]
    unsigned char*  Y8  = (unsigned char*)(wsb + 4232720ll * 4);   // fp8 [(NN+1)*128]
    unsigned char*  Y82 = (unsigned char*)(wsb + 7432752ll * 4);   // fp8 [(NN+1)*128]

    // zero bincnt + gcount + hg_sum
    hipMemsetAsync(d_ws, 0, (size_t)8768 * 4, stream);

    // K1: bin hist || graph counts || Wt + dummy rows
    k_pre<<<2 * NBIN + 129, 256, 0, stream>>>(dst, gid, bincnt, gcount, W1, W2,
                                              W1t, W2t,
                                              (unsigned int*)(Y8 + (size_t)NN * FD),
                                              (unsigned int*)(Y82 + (size_t)NN * FD));
    // K2: bin scan
    k_boff<<<1, 512, 0, stream>>>(bincnt, pstart, bcur);
    // K3: LDS-multisplit bin append (first NGFILL blocks) || gemm1
    k_mix<<<NGFILL + NGEMM1, 256, 0, stream>>>(src, dst, bcur, pbuf, feat, W1t, Y8);
    // K4: bin-local CSR build (pad 8)
    k_fill2<<<NBIN, 256, 0, stream>>>(pbuf, pstart, bcur, degi, off, eidx);
    // K5: agg1 + fused gemm2 -> Y82
    k_aggmm<<<NN / 16, 256, 0, stream>>>(Y8, off, degi, eidx, b1, W2t, Y82);
    // K6: agg2 + per-graph pooling
    k_aggp<<<NN / 16, 256, 0, stream>>>(Y82, off, degi, eidx, b2, gid, hg_sum);
    // K7: pool divide + decoder
    k_dec<<<NG, 128, 0, stream>>>(hg_sum, gcount, Wd1, bd1, Wd2, bd2, out);
}